// Round 4
// baseline (188.240 us; speedup 1.0000x reference)
//
#include <hip/hip_runtime.h>

// Segmented CRF forward (OneCrfCCKSDecoder), exp-domain, R4.
// T=128, B=512, E=128, EVENTLEN=8, NEG=-10000.
//
// R3 post-mortem: serial-LATENCY bound (0.5 waves/SIMD, no hiding); the
// every-step renorm butterfly (6 dependent ds_bpermute shuffles ~700cyc)
// dominated. R4: (a) DPP-based wave reductions (row_shr/bcast + readlane,
// ~50cyc dependent), (b) TWO batches per wave (256 wgs x 64thr, 1 wave/CU,
// every CU busy, 2 independent dep chains interleaved, E-regs reused 2x).
// Expected bound: VALU issue (~256 v_dot2 x 2cyc/step) ~= 32us.
//
// Numerics (validated R3, absmax 0.0): state fv[j] = M + log u[j]; renorm
// u by exact wave-max every update step => u<=1, h = u*exp(feat) <= ~250
// (f16-safe). Rows 0 of exp(T) and te[127] are exactly 0, matching fp32
// exp(-10000)=0 in the reference.

typedef _Float16 h2_t __attribute__((ext_vector_type(2)));
typedef _Float16 h8_t __attribute__((ext_vector_type(8)));

#define NEG_VAL (-10000.0f)

#if __has_builtin(__builtin_amdgcn_fdot2)
#define FDOT2(a, b, c) __builtin_amdgcn_fdot2((a), (b), (c), false)
#else
static __device__ __forceinline__ float FDOT2(h2_t a, h2_t b, float c) {
    return c + (float)a[0] * (float)b[0] + (float)a[1] * (float)b[1];
}
#endif

// ---- DPP wave-64 reductions (VALU-pipe, no LDS round trips) ----
// update_dpp(old, src, ctrl, row_mask, bank_mask, bound_ctrl):
// disabled/invalid lanes receive `old` (identity element).

template <int CTRL, int RMASK>
static __device__ __forceinline__ float dpp_ident(float old_, float src) {
    return __builtin_bit_cast(float, __builtin_amdgcn_update_dpp(
        __builtin_bit_cast(int, old_), __builtin_bit_cast(int, src),
        CTRL, RMASK, 0xf, false));
}

static __device__ __forceinline__ float wave_max_dpp(float v) {
    v = fmaxf(v, dpp_ident<0x111, 0xf>(v, v));   // row_shr:1
    v = fmaxf(v, dpp_ident<0x112, 0xf>(v, v));   // row_shr:2
    v = fmaxf(v, dpp_ident<0x114, 0xf>(v, v));   // row_shr:4
    v = fmaxf(v, dpp_ident<0x118, 0xf>(v, v));   // row_shr:8
    v = fmaxf(v, dpp_ident<0x142, 0xa>(v, v));   // row_bcast:15 -> rows 1,3
    v = fmaxf(v, dpp_ident<0x143, 0xc>(v, v));   // row_bcast:31 -> rows 2,3
    return __builtin_bit_cast(float,
        __builtin_amdgcn_readlane(__builtin_bit_cast(int, v), 63));
}

static __device__ __forceinline__ float wave_sum_dpp(float v) {
    v = v + dpp_ident<0x111, 0xf>(0.0f, v);
    v = v + dpp_ident<0x112, 0xf>(0.0f, v);
    v = v + dpp_ident<0x114, 0xf>(0.0f, v);
    v = v + dpp_ident<0x118, 0xf>(0.0f, v);
    v = v + dpp_ident<0x142, 0xa>(0.0f, v);
    v = v + dpp_ident<0x143, 0xc>(0.0f, v);
    return __builtin_bit_cast(float,
        __builtin_amdgcn_readlane(__builtin_bit_cast(int, v), 63));
}

__global__ __launch_bounds__(64)
void crf_fwd(const float* __restrict__ feats,   // [128][512][128]
             const float* __restrict__ trans,   // [128][128]
             float* __restrict__ out)
{
    const int L  = threadIdx.x;        // 0..63
    const int bA = 2 * blockIdx.x;     // two batches per wave
    const int bB = bA + 1;
    const int j0 = 2 * L;
    const int j1 = 2 * L + 1;

    // exp(trans) rows j0, j1, f16-packed over k: 128 VGPRs, shared by both
    // batches.
    h2_t E0[64], E1[64];
    {
        const float4* r0 = (const float4*)(trans + (size_t)j0 * 128);
        const float4* r1 = (const float4*)(trans + (size_t)j1 * 128);
        #pragma unroll
        for (int i = 0; i < 32; ++i) {
            float4 a = r0[i];
            float4 c = r1[i];
            h2_t p;
            p[0] = (_Float16)__expf(a.x); p[1] = (_Float16)__expf(a.y); E0[2*i]   = p;
            p[0] = (_Float16)__expf(a.z); p[1] = (_Float16)__expf(a.w); E0[2*i+1] = p;
            p[0] = (_Float16)__expf(c.x); p[1] = (_Float16)__expf(c.y); E1[2*i]   = p;
            p[0] = (_Float16)__expf(c.z); p[1] = (_Float16)__expf(c.w); E1[2*i+1] = p;
        }
    }
    const float te0 = __expf(trans[127 * 128 + j0]);  // exp(T[127, j0])
    const float te1 = __expf(trans[127 * 128 + j1]);

    __shared__ __align__(16) h2_t hbuf[2][64];   // [batch][L] packed h pair

    // feat pair [t][b][2L..2L+1]; per-t stride 65536 floats = 32768 float2
    const float2* fbA = (const float2*)(feats + (size_t)bA * 128 + 2 * L);
    const float2* fbB = (const float2*)(feats + (size_t)bB * 128 + 2 * L);
    #define FSTR 32768

    // pipeline: ef* = exp(feat[t]); rA1 = raw feat[t+1]; rA2 = raw feat[t+2]
    float2 lA = fbA[1 * FSTR], lB = fbB[1 * FSTR];
    float2 rA1 = fbA[2 * FSTR], rB1 = fbB[2 * FSTR];
    float2 rA2 = fbA[3 * FSTR], rB2 = fbB[3 * FSTR];
    float efA0 = __expf(lA.x), efA1 = __expf(lA.y);
    float efB0 = __expf(lB.x), efB1 = __expf(lB.y);

    float uA0 = 1.0f, uA1 = 1.0f, uB0 = 1.0f, uB1 = 1.0f;
    float MA = (bA == 0) ? 0.0f : NEG_VAL;   // init_fv zeroes only batch-0 row
    float MB = NEG_VAL;                      // bB is odd, never 0
    float alphaA = 0.0f, alphaB = 0.0f;

    for (int t = 1; t < 128; ++t) {
        const bool upd = (t & 7) != 0;

        if (upd) {
            // publish h = u * exp(feat[t]) as packed f16 (u<=1 => f16-safe)
            h2_t hA; hA[0] = (_Float16)(uA0 * efA0); hA[1] = (_Float16)(uA1 * efA1);
            h2_t hB; hB[0] = (_Float16)(uB0 * efB0); hB[1] = (_Float16)(uB1 * efB1);
            hbuf[0][L] = hA;
            hbuf[1][L] = hB;
            __syncthreads();
        }

        // rotate feat pipeline (global loads issued far from use)
        float2 nA = {0.0f, 0.0f}, nB = {0.0f, 0.0f};
        if (t + 3 < 128) {
            nA = fbA[(size_t)(t + 3) * FSTR];
            nB = fbB[(size_t)(t + 3) * FSTR];
        }
        const float enA0 = __expf(rA1.x), enA1 = __expf(rA1.y);  // exp(feat[t+1])
        const float enB0 = __expf(rB1.x), enB1 = __expf(rB1.y);
        rA1 = rA2; rA2 = nA;
        rB1 = rB2; rB2 = nB;

        if (upd) {
            // ---- DP update: s[j] = sum_k h[k] * E[j,k], both batches ----
            const h8_t* hvA = (const h8_t*)hbuf[0];
            const h8_t* hvB = (const h8_t*)hbuf[1];
            float aA0 = 0.f, bA0 = 0.f, aA1 = 0.f, bA1 = 0.f;
            float aB0 = 0.f, bB0 = 0.f, aB1 = 0.f, bB1 = 0.f;
            #pragma unroll
            for (int i = 0; i < 16; ++i) {
                h8_t vA = hvA[i];       // wave-uniform broadcast, 8 h values
                h8_t vB = hvB[i];
                h2_t p0; p0[0] = vA[0]; p0[1] = vA[1];
                h2_t p1; p1[0] = vA[2]; p1[1] = vA[3];
                h2_t p2; p2[0] = vA[4]; p2[1] = vA[5];
                h2_t p3; p3[0] = vA[6]; p3[1] = vA[7];
                h2_t q0; q0[0] = vB[0]; q0[1] = vB[1];
                h2_t q1; q1[0] = vB[2]; q1[1] = vB[3];
                h2_t q2; q2[0] = vB[4]; q2[1] = vB[5];
                h2_t q3; q3[0] = vB[6]; q3[1] = vB[7];
                aA0 = FDOT2(E0[4*i + 0], p0, aA0);
                bA0 = FDOT2(E0[4*i + 1], p1, bA0);
                aA0 = FDOT2(E0[4*i + 2], p2, aA0);
                bA0 = FDOT2(E0[4*i + 3], p3, bA0);
                aA1 = FDOT2(E1[4*i + 0], p0, aA1);
                bA1 = FDOT2(E1[4*i + 1], p1, bA1);
                aA1 = FDOT2(E1[4*i + 2], p2, aA1);
                bA1 = FDOT2(E1[4*i + 3], p3, bA1);
                aB0 = FDOT2(E0[4*i + 0], q0, aB0);
                bB0 = FDOT2(E0[4*i + 1], q1, bB0);
                aB0 = FDOT2(E0[4*i + 2], q2, aB0);
                bB0 = FDOT2(E0[4*i + 3], q3, bB0);
                aB1 = FDOT2(E1[4*i + 0], q0, aB1);
                bB1 = FDOT2(E1[4*i + 1], q1, bB1);
                aB1 = FDOT2(E1[4*i + 2], q2, aB1);
                bB1 = FDOT2(E1[4*i + 3], q3, bB1);
            }
            float sA0 = aA0 + bA0, sA1 = aA1 + bA1;
            float sB0 = aB0 + bB0, sB1 = aB1 + bB1;

            // exact renorm via DPP max (two independent chains overlap)
            float cA = wave_max_dpp(fmaxf(sA0, sA1));
            float cB = wave_max_dpp(fmaxf(sB0, sB1));
            const float iA = __builtin_amdgcn_rcpf(cA);
            const float iB = __builtin_amdgcn_rcpf(cB);
            uA0 = sA0 * iA; uA1 = sA1 * iA;
            uB0 = sB0 * iB; uB1 = sB1 * iB;
            MA += __logf(cA);           // off the u-critical path
            MB += __logf(cB);
        } else {
            // ---- event boundary: alpha += M + log(sum_j u[j]*te[j]) ----
            float rA = wave_sum_dpp(uA0 * te0 + uA1 * te1);
            float rB = wave_sum_dpp(uB0 * te0 + uB1 * te1);
            alphaA += MA + __logf(rA);
            alphaB += MB + __logf(rB);
        }

        efA0 = enA0; efA1 = enA1;
        efB0 = enB0; efB1 = enB1;
    }

    // terminal accumulation
    {
        float rA = wave_sum_dpp(uA0 * te0 + uA1 * te1);
        float rB = wave_sum_dpp(uB0 * te0 + uB1 * te1);
        alphaA += MA + __logf(rA);
        alphaB += MB + __logf(rB);
    }

    if (L == 0)
        atomicAdd(out, (alphaA + alphaB) * (1.0f / (512.0f * 16.0f)));
}

extern "C" void kernel_launch(void* const* d_in, const int* in_sizes, int n_in,
                              void* d_out, int out_size, void* d_ws, size_t ws_size,
                              hipStream_t stream) {
    const float* feats = (const float*)d_in[0];   // [128,512,128] f32
    const float* trans = (const float*)d_in[1];   // [128,128] f32
    float* out = (float*)d_out;                   // scalar f32

    hipMemsetAsync(out, 0, sizeof(float), stream);
    crf_fwd<<<256, 64, 0, stream>>>(feats, trans, out);
}

// Round 5
// 144.699 us; speedup vs baseline: 1.3009x; 1.3009x over previous
//
#include <hip/hip_runtime.h>

// Segmented CRF forward (OneCrfCCKSDecoder), exp-domain, R5.
// T=128, B=512, E=128, EVENTLEN=8, NEG=-10000.
//
// R4 post-mortem: parallelism is capped by B=512 -> max 512 waves (2 SIMDs/CU
// at 1 batch/wave). R4's 1-wave/CU config starved issue. R5 = R3 layout
// (512 wgs x 64thr, 1 batch/wave) + the serial-cost fixes:
//  - DPP wave reductions (R4-validated, ~60cyc) instead of LDS shuffles (~600)
//  - raw `s_waitcnt lgkmcnt(0)` instead of __syncthreads(): orders the LDS
//    h write->read WITHOUT draining vmcnt, so feat prefetch loads stay in
//    flight across steps (syncthreads was exposing global latency per step)
//  - __launch_bounds__(64,1): 512 arch-VGPR budget so the 128-reg exp(T)
//    table stays in VGPRs (R3's VGPR_Count=84 => table was in AGPRs)
//
// Numerics (R3/R4-validated, absmax 0.0): state fv[j] = M + log u[j]; exact
// renorm by wave-max every update step => u<=1, h = u*exp(feat) <= ~250
// (f16-safe). Row 0 of exp(T) and te[127] are exactly 0, matching fp32
// exp(-10000)=0 in the reference.

typedef _Float16 h2_t __attribute__((ext_vector_type(2)));
typedef _Float16 h8_t __attribute__((ext_vector_type(8)));

#define NEG_VAL (-10000.0f)

#if __has_builtin(__builtin_amdgcn_fdot2)
#define FDOT2(a, b, c) __builtin_amdgcn_fdot2((a), (b), (c), false)
#else
static __device__ __forceinline__ float FDOT2(h2_t a, h2_t b, float c) {
    return c + (float)a[0] * (float)b[0] + (float)a[1] * (float)b[1];
}
#endif

// LDS-ordering-only fence: wave-private h buffer, single wave per wg, so we
// only need ds write->read ordering. Crucially does NOT wait vmcnt.
#define LDS_FENCE() asm volatile("s_waitcnt lgkmcnt(0)" ::: "memory")

// ---- DPP wave-64 reductions (VALU-pipe, validated in R4) ----
template <int CTRL, int RMASK>
static __device__ __forceinline__ float dpp_ident(float old_, float src) {
    return __builtin_bit_cast(float, __builtin_amdgcn_update_dpp(
        __builtin_bit_cast(int, old_), __builtin_bit_cast(int, src),
        CTRL, RMASK, 0xf, false));
}

static __device__ __forceinline__ float wave_max_dpp(float v) {
    v = fmaxf(v, dpp_ident<0x111, 0xf>(v, v));   // row_shr:1
    v = fmaxf(v, dpp_ident<0x112, 0xf>(v, v));   // row_shr:2
    v = fmaxf(v, dpp_ident<0x114, 0xf>(v, v));   // row_shr:4
    v = fmaxf(v, dpp_ident<0x118, 0xf>(v, v));   // row_shr:8
    v = fmaxf(v, dpp_ident<0x142, 0xa>(v, v));   // row_bcast:15 -> rows 1,3
    v = fmaxf(v, dpp_ident<0x143, 0xc>(v, v));   // row_bcast:31 -> rows 2,3
    return __builtin_bit_cast(float,
        __builtin_amdgcn_readlane(__builtin_bit_cast(int, v), 63));
}

static __device__ __forceinline__ float wave_sum_dpp(float v) {
    v = v + dpp_ident<0x111, 0xf>(0.0f, v);
    v = v + dpp_ident<0x112, 0xf>(0.0f, v);
    v = v + dpp_ident<0x114, 0xf>(0.0f, v);
    v = v + dpp_ident<0x118, 0xf>(0.0f, v);
    v = v + dpp_ident<0x142, 0xa>(0.0f, v);
    v = v + dpp_ident<0x143, 0xc>(0.0f, v);
    return __builtin_bit_cast(float,
        __builtin_amdgcn_readlane(__builtin_bit_cast(int, v), 63));
}

__global__ __launch_bounds__(64, 1)   // 1 wave/EU min -> full 512-VGPR budget
void crf_fwd(const float* __restrict__ feats,   // [128][512][128]
             const float* __restrict__ trans,   // [128][128]
             float* __restrict__ out)
{
    const int L  = threadIdx.x;     // 0..63
    const int b  = blockIdx.x;      // one batch per wave
    const int j0 = 2 * L;
    const int j1 = 2 * L + 1;

    // exp(trans) rows j0, j1, f16-packed over k: 128 VGPRs.
    h2_t E0[64], E1[64];
    {
        const float4* r0 = (const float4*)(trans + (size_t)j0 * 128);
        const float4* r1 = (const float4*)(trans + (size_t)j1 * 128);
        #pragma unroll
        for (int i = 0; i < 32; ++i) {
            float4 a = r0[i];
            float4 c = r1[i];
            h2_t p;
            p[0] = (_Float16)__expf(a.x); p[1] = (_Float16)__expf(a.y); E0[2*i]   = p;
            p[0] = (_Float16)__expf(a.z); p[1] = (_Float16)__expf(a.w); E0[2*i+1] = p;
            p[0] = (_Float16)__expf(c.x); p[1] = (_Float16)__expf(c.y); E1[2*i]   = p;
            p[0] = (_Float16)__expf(c.z); p[1] = (_Float16)__expf(c.w); E1[2*i+1] = p;
        }
    }
    const float te0 = __expf(trans[127 * 128 + j0]);  // exp(T[127, j0])
    const float te1 = __expf(trans[127 * 128 + j1]);

    __shared__ __align__(16) h2_t hbuf[64];   // wave-private packed h

    // feat pair [t][b][2L..2L+1]; per-t stride 65536 floats = 32768 float2
    const float2* fb = (const float2*)(feats + (size_t)b * 128 + 2 * L);
    #define FSTR 32768

    // pipeline: ef = exp(feat[t]); r1v = raw feat[t+1]; r2v = raw feat[t+2]
    float2 l1  = fb[1 * FSTR];
    float2 r1v = fb[2 * FSTR];
    float2 r2v = fb[3 * FSTR];
    float ef0 = __expf(l1.x), ef1 = __expf(l1.y);

    float u0 = 1.0f, u1 = 1.0f;
    float M     = (b == 0) ? 0.0f : NEG_VAL;  // init_fv zeroes only batch-0 row
    float alpha = 0.0f;

    for (int t = 1; t < 128; ++t) {
        const bool upd = (t & 7) != 0;

        if (upd) {
            // publish h = u * exp(feat[t]) as packed f16 (u<=1 => f16-safe)
            h2_t hh;
            hh[0] = (_Float16)(u0 * ef0);
            hh[1] = (_Float16)(u1 * ef1);
            hbuf[L] = hh;
            LDS_FENCE();                 // order write -> broadcast reads
        }

        // rotate feat pipeline (global loads stay in flight; no vmcnt drain)
        float2 nf = {0.0f, 0.0f};
        if (t + 3 < 128) nf = fb[(size_t)(t + 3) * FSTR];
        const float en0 = __expf(r1v.x), en1 = __expf(r1v.y);  // exp(feat[t+1])
        r1v = r2v; r2v = nf;

        if (upd) {
            // ---- DP update: s[j] = sum_k h[k] * E[j,k] ----
            const h8_t* hv = (const h8_t*)hbuf;
            float a0 = 0.f, b0 = 0.f;    // two chains for j0
            float a1 = 0.f, b1 = 0.f;    // two chains for j1
            #pragma unroll
            for (int i = 0; i < 16; ++i) {
                h8_t v = hv[i];          // wave-uniform broadcast, 8 h values
                h2_t p0; p0[0] = v[0]; p0[1] = v[1];
                h2_t p1; p1[0] = v[2]; p1[1] = v[3];
                h2_t p2; p2[0] = v[4]; p2[1] = v[5];
                h2_t p3; p3[0] = v[6]; p3[1] = v[7];
                a0 = FDOT2(E0[4*i + 0], p0, a0);
                b0 = FDOT2(E0[4*i + 1], p1, b0);
                a0 = FDOT2(E0[4*i + 2], p2, a0);
                b0 = FDOT2(E0[4*i + 3], p3, b0);
                a1 = FDOT2(E1[4*i + 0], p0, a1);
                b1 = FDOT2(E1[4*i + 1], p1, b1);
                a1 = FDOT2(E1[4*i + 2], p2, a1);
                b1 = FDOT2(E1[4*i + 3], p3, b1);
            }
            float s0 = a0 + b0;
            float s1 = a1 + b1;

            // exact renorm via DPP max (~60cyc dependent)
            float c = wave_max_dpp(fmaxf(s0, s1));
            const float inv = __builtin_amdgcn_rcpf(c);
            u0 = s0 * inv;
            u1 = s1 * inv;
            M += __logf(c);              // off the u-critical path
        } else {
            // ---- event boundary: alpha += M + log(sum_j u[j]*te[j]) ----
            float r = wave_sum_dpp(u0 * te0 + u1 * te1);
            alpha += M + __logf(r);      // wave-uniform
        }

        ef0 = en0; ef1 = en1;
    }

    // terminal accumulation
    {
        float r = wave_sum_dpp(u0 * te0 + u1 * te1);
        alpha += M + __logf(r);
    }

    if (L == 0)
        atomicAdd(out, alpha * (1.0f / (512.0f * 16.0f)));
}

extern "C" void kernel_launch(void* const* d_in, const int* in_sizes, int n_in,
                              void* d_out, int out_size, void* d_ws, size_t ws_size,
                              hipStream_t stream) {
    const float* feats = (const float*)d_in[0];   // [128,512,128] f32
    const float* trans = (const float*)d_in[1];   // [128,128] f32
    float* out = (float*)d_out;                   // scalar f32

    hipMemsetAsync(out, 0, sizeof(float), stream);
    crf_fwd<<<512, 64, 0, stream>>>(feats, trans, out);
}

// Round 6
// 144.405 us; speedup vs baseline: 1.3036x; 1.0020x over previous
//
#include <hip/hip_runtime.h>

// Segmented CRF forward (OneCrfCCKSDecoder), exp-domain, R6.
// T=128, B=512, E=128, EVENTLEN=8, NEG=-10000.
//
// R5 post-mortem: 84.7us = ~1600cyc/step serial; remaining chain includes
// the exact renorm (DPP max + rcp) BETWEEN dot output and next h-write.
// R6: one-step-STALE renorm computed in the shadow of the next step's LDS
// wait + dot issue. Scale applied to h at step t is 1/(16*max(s_{t-1})),
// with M += log(c)+log(16) bookkeeping at application time => numerically
// EXACT (up to rcp/log rounding ~1e-7/step). Critical chain is now just:
// dot -> mul(ef*inv prefolded) -> cvt -> ds_write -> lgkm -> ds_read -> dot.
//
// f16 safety: h <= r * 245/16 where r = one-step max ratio (realistically
// <~5) => h <~ 80 vs f16 max 65504. u (f32) self-normalizes to O(20)/step.
// Row 0 of exp(T) and te[127] are exactly 0, matching fp32 exp(-10000)=0.
//
// Kept from R5 (validated): 512 wgs x 64 thr, 1 batch/wave, E f16-packed in
// 128 regs, lgkmcnt-only LDS fence (no vmcnt drain -> feat prefetch stays in
// flight), DPP wave reductions, launch_bounds(64,1).

typedef _Float16 h2_t __attribute__((ext_vector_type(2)));
typedef _Float16 h8_t __attribute__((ext_vector_type(8)));

#define NEG_VAL (-10000.0f)
#define LOG16   2.7725887222397812f

#if __has_builtin(__builtin_amdgcn_fdot2)
#define FDOT2(a, b, c) __builtin_amdgcn_fdot2((a), (b), (c), false)
#else
static __device__ __forceinline__ float FDOT2(h2_t a, h2_t b, float c) {
    return c + (float)a[0] * (float)b[0] + (float)a[1] * (float)b[1];
}
#endif

// LDS-ordering-only fence (wave-private h buffer): does NOT drain vmcnt.
#define LDS_FENCE() asm volatile("s_waitcnt lgkmcnt(0)" ::: "memory")

// ---- DPP wave-64 reductions (VALU pipe; validated R4/R5) ----
template <int CTRL, int RMASK>
static __device__ __forceinline__ float dpp_ident(float old_, float src) {
    return __builtin_bit_cast(float, __builtin_amdgcn_update_dpp(
        __builtin_bit_cast(int, old_), __builtin_bit_cast(int, src),
        CTRL, RMASK, 0xf, false));
}

static __device__ __forceinline__ float wave_max_dpp(float v) {
    v = fmaxf(v, dpp_ident<0x111, 0xf>(v, v));   // row_shr:1
    v = fmaxf(v, dpp_ident<0x112, 0xf>(v, v));   // row_shr:2
    v = fmaxf(v, dpp_ident<0x114, 0xf>(v, v));   // row_shr:4
    v = fmaxf(v, dpp_ident<0x118, 0xf>(v, v));   // row_shr:8
    v = fmaxf(v, dpp_ident<0x142, 0xa>(v, v));   // row_bcast:15 -> rows 1,3
    v = fmaxf(v, dpp_ident<0x143, 0xc>(v, v));   // row_bcast:31 -> rows 2,3
    return __builtin_bit_cast(float,
        __builtin_amdgcn_readlane(__builtin_bit_cast(int, v), 63));
}

static __device__ __forceinline__ float wave_sum_dpp(float v) {
    v = v + dpp_ident<0x111, 0xf>(0.0f, v);
    v = v + dpp_ident<0x112, 0xf>(0.0f, v);
    v = v + dpp_ident<0x114, 0xf>(0.0f, v);
    v = v + dpp_ident<0x118, 0xf>(0.0f, v);
    v = v + dpp_ident<0x142, 0xa>(0.0f, v);
    v = v + dpp_ident<0x143, 0xc>(0.0f, v);
    return __builtin_bit_cast(float,
        __builtin_amdgcn_readlane(__builtin_bit_cast(int, v), 63));
}

__global__ __launch_bounds__(64, 1)
void crf_fwd(const float* __restrict__ feats,   // [128][512][128]
             const float* __restrict__ trans,   // [128][128]
             float* __restrict__ out)
{
    const int L  = threadIdx.x;     // 0..63
    const int b  = blockIdx.x;      // one batch per wave
    const int j0 = 2 * L;
    const int j1 = 2 * L + 1;

    // exp(trans) rows j0, j1, f16-packed over k: 128 regs.
    h2_t E0[64], E1[64];
    {
        const float4* r0 = (const float4*)(trans + (size_t)j0 * 128);
        const float4* r1 = (const float4*)(trans + (size_t)j1 * 128);
        #pragma unroll
        for (int i = 0; i < 32; ++i) {
            float4 a = r0[i];
            float4 c = r1[i];
            h2_t p;
            p[0] = (_Float16)__expf(a.x); p[1] = (_Float16)__expf(a.y); E0[2*i]   = p;
            p[0] = (_Float16)__expf(a.z); p[1] = (_Float16)__expf(a.w); E0[2*i+1] = p;
            p[0] = (_Float16)__expf(c.x); p[1] = (_Float16)__expf(c.y); E1[2*i]   = p;
            p[0] = (_Float16)__expf(c.z); p[1] = (_Float16)__expf(c.w); E1[2*i+1] = p;
        }
    }
    const float te0 = __expf(trans[127 * 128 + j0]);  // exp(T[127, j0])
    const float te1 = __expf(trans[127 * 128 + j1]);

    __shared__ __align__(16) h2_t hbuf[64];   // wave-private packed h

    // feat pair [t][b][2L..2L+1]; per-t stride 65536 floats = 32768 float2
    const float2* fb = (const float2*)(feats + (size_t)b * 128 + 2 * L);
    #define FSTR 32768

    // feat pipeline: ef = exp(feat[t]); r1v/r2v = raw feat[t+1]/[t+2]
    float2 l1  = fb[1 * FSTR];
    float2 r1v = fb[2 * FSTR];
    float2 r2v = fb[3 * FSTR];
    float ef0 = __expf(l1.x), ef1 = __expf(l1.y);

    float u0 = 1.0f, u1 = 1.0f;
    float M     = (b == 0) ? 0.0f : NEG_VAL;  // init_fv zeroes only batch-0 row
    float alpha = 0.0f;

    // stale-renorm pipeline: factor applied to h THIS step (and its log).
    // Initially u==1 -> c=1, apply 1/16 safety only.
    float inv_apply  = 0.0625f;
    float logc_apply = LOG16;

    #pragma unroll 8
    for (int t = 1; t < 128; ++t) {
        const bool upd = (t & 7) != 0;

        if (upd) {
            // publish h = u * ef * inv_apply (stale scale, f16-safe)
            M += logc_apply;             // exact bookkeeping of applied scale
            h2_t hh;
            hh[0] = (_Float16)(u0 * (ef0 * inv_apply));
            hh[1] = (_Float16)(u1 * (ef1 * inv_apply));
            hbuf[L] = hh;
            LDS_FENCE();                 // order write -> broadcast reads
        }

        // rotate feat pipeline (global loads stay in flight; no vmcnt drain)
        float2 nf = {0.0f, 0.0f};
        if (t + 3 < 128) nf = fb[(size_t)(t + 3) * FSTR];
        const float en0 = __expf(r1v.x), en1 = __expf(r1v.y);  // exp(feat[t+1])
        r1v = r2v; r2v = nf;

        if (upd) {
            // ---- shadow work: next step's scale from CURRENT u (= s_{t-1})
            // (independent of the dot below; overlaps LDS latency + issue)
            float c = wave_max_dpp(fmaxf(u0, u1));
            float inv_next  = __builtin_amdgcn_rcpf(c) * 0.0625f;
            float logc_next = __logf(c) + LOG16;

            // ---- DP update: s[j] = sum_k h[k] * E[j,k] ----
            const h8_t* hv = (const h8_t*)hbuf;
            float a0 = 0.f, b0 = 0.f;    // two chains for j0
            float a1 = 0.f, b1 = 0.f;    // two chains for j1
            #pragma unroll
            for (int i = 0; i < 16; ++i) {
                h8_t v = hv[i];          // wave-uniform broadcast, 8 h values
                h2_t p0; p0[0] = v[0]; p0[1] = v[1];
                h2_t p1; p1[0] = v[2]; p1[1] = v[3];
                h2_t p2; p2[0] = v[4]; p2[1] = v[5];
                h2_t p3; p3[0] = v[6]; p3[1] = v[7];
                a0 = FDOT2(E0[4*i + 0], p0, a0);
                b0 = FDOT2(E0[4*i + 1], p1, b0);
                a0 = FDOT2(E0[4*i + 2], p2, a0);
                b0 = FDOT2(E0[4*i + 3], p3, b0);
                a1 = FDOT2(E1[4*i + 0], p0, a1);
                b1 = FDOT2(E1[4*i + 1], p1, b1);
                a1 = FDOT2(E1[4*i + 2], p2, a1);
                b1 = FDOT2(E1[4*i + 3], p3, b1);
            }
            u0 = a0 + b0;                // raw (scale folded into h; M exact)
            u1 = a1 + b1;

            inv_apply  = inv_next;
            logc_apply = logc_next;
        } else {
            // ---- event boundary: alpha += M + log(sum_j u[j]*te[j]) ----
            float r = wave_sum_dpp(u0 * te0 + u1 * te1);
            alpha += M + __logf(r);      // wave-uniform
        }

        ef0 = en0; ef1 = en1;
    }

    // terminal accumulation
    {
        float r = wave_sum_dpp(u0 * te0 + u1 * te1);
        alpha += M + __logf(r);
    }

    if (L == 0)
        atomicAdd(out, alpha * (1.0f / (512.0f * 16.0f)));
}

extern "C" void kernel_launch(void* const* d_in, const int* in_sizes, int n_in,
                              void* d_out, int out_size, void* d_ws, size_t ws_size,
                              hipStream_t stream) {
    const float* feats = (const float*)d_in[0];   // [128,512,128] f32
    const float* trans = (const float*)d_in[1];   // [128,128] f32
    float* out = (float*)d_out;                   // scalar f32

    hipMemsetAsync(out, 0, sizeof(float), stream);
    crf_fwd<<<512, 64, 0, stream>>>(feats, trans, out);
}